// Round 13
// baseline (316.150 us; speedup 1.0000x reference)
//
#include <hip/hip_runtime.h>

typedef unsigned short u16;
typedef short bf16x8 __attribute__((ext_vector_type(8)));
typedef float f32x4 __attribute__((ext_vector_type(4)));

__device__ __forceinline__ u16 f2bf(float f) {
  union { float f; unsigned u; } c; c.f = f;
  unsigned r = (c.u + 0x7FFFu + ((c.u >> 16) & 1u)) >> 16;
  return (u16)r;
}
__device__ __forceinline__ float bf2f(u16 h) {
  union { unsigned u; float f; } c; c.u = ((unsigned)h) << 16;
  return c.f;
}
__device__ __forceinline__ void gload16(const void* g, void* l) {
  __builtin_amdgcn_global_load_lds(
      (const __attribute__((address_space(1))) unsigned*)g,
      (__attribute__((address_space(3))) unsigned*)l, 16, 0, 0);
}

// ---------------------------------------------------------------------------
// Weight prep: w_qkv [512,1536] -> wqkvT bf16 [1536,512]; w_out -> woutT [512,512]
// ---------------------------------------------------------------------------
__global__ __launch_bounds__(256) void prep_weights(
    const float* __restrict__ w_qkv, const float* __restrict__ w_out,
    u16* __restrict__ wqkvT, u16* __restrict__ woutT) {
  int i = blockIdx.x * 256 + threadIdx.x;
  const int T1 = 1536 * 512;
  if (i < T1) {
    int n = i >> 9, c = i & 511;
    wqkvT[i] = f2bf(w_qkv[(size_t)c * 1536 + n]);
  } else {
    int j = i - T1;
    int n = j >> 9, c = j & 511;
    woutT[j] = f2bf(w_out[(size_t)c * 512 + n]);
  }
}

// ---------------------------------------------------------------------------
// GroupNorm: x fp32 [32,1024,512] -> z bf16; 32 groups of 16 ch
// ---------------------------------------------------------------------------
__global__ __launch_bounds__(256) void groupnorm_k(
    const float* __restrict__ x, const float* __restrict__ scale,
    const float* __restrict__ bias, u16* __restrict__ z) {
  const int blk = blockIdx.x, b = blk >> 5, g = blk & 31;
  const float* xb = x + (size_t)b * 524288 + g * 16;
  u16* zb = z + (size_t)b * 524288 + g * 16;
  const int tid = threadIdx.x, lane = tid & 63, wid = tid >> 6;

  float4 vv[16];
  float s = 0.f, ss = 0.f;
#pragma unroll
  for (int i = 0; i < 16; ++i) {
    int e = (i * 256 + tid) * 4;
    int hw = e >> 4, j = e & 15;
    vv[i] = *(const float4*)&xb[(size_t)hw * 512 + j];
    s += vv[i].x + vv[i].y + vv[i].z + vv[i].w;
    ss += vv[i].x * vv[i].x + vv[i].y * vv[i].y + vv[i].z * vv[i].z + vv[i].w * vv[i].w;
  }
#pragma unroll
  for (int off = 32; off; off >>= 1) {
    s += __shfl_xor(s, off);
    ss += __shfl_xor(ss, off);
  }
  __shared__ float rs[4], rq[4];
  if (!lane) { rs[wid] = s; rq[wid] = ss; }
  __syncthreads();
  float S_ = rs[0] + rs[1] + rs[2] + rs[3];
  float Q_ = rq[0] + rq[1] + rq[2] + rq[3];
  const float inv_n = 1.f / 16384.f;
  float mean = S_ * inv_n;
  float var = Q_ * inv_n - mean * mean;
  float rstd = rsqrtf(var + 1e-5f);

  int j0 = (tid * 4) & 15;
  float sc0 = scale[g * 16 + j0 + 0] * rstd, sc1 = scale[g * 16 + j0 + 1] * rstd;
  float sc2 = scale[g * 16 + j0 + 2] * rstd, sc3 = scale[g * 16 + j0 + 3] * rstd;
  float bi0 = bias[g * 16 + j0 + 0] - mean * sc0, bi1 = bias[g * 16 + j0 + 1] - mean * sc1;
  float bi2 = bias[g * 16 + j0 + 2] - mean * sc2, bi3 = bias[g * 16 + j0 + 3] - mean * sc3;
#pragma unroll
  for (int i = 0; i < 16; ++i) {
    int e = (i * 256 + tid) * 4;
    int hw = e >> 4, j = e & 15;
    ushort4 o;
    o.x = f2bf(vv[i].x * sc0 + bi0);
    o.y = f2bf(vv[i].y * sc1 + bi1);
    o.z = f2bf(vv[i].z * sc2 + bi2);
    o.w = f2bf(vv[i].w * sc3 + bi3);
    *(ushort4*)&zb[(size_t)hw * 512 + j] = o;
  }
}

// ---------------------------------------------------------------------------
// Deep-ring GEMM (round-9, unchanged): 256x256 tile, BK=32, 4-buffer ring,
// 1 barrier + counted vmcnt(8) per tile.
// EPI 0: q (scaled by 1/sqrt(512)), k rowmajor, v -> TRANSPOSED [b][c][p]
// EPI 2: fp32 +bias+resid
// ---------------------------------------------------------------------------
#define QSCALE 0.04419417382415922f

template <int EPI>
__global__ __launch_bounds__(512, 2) void gemm_ring(
    const u16* __restrict__ A, const u16* __restrict__ Bt,
    int gx, int gxy, int N, int K,
    int sched, int sp1, int sp2,
    long long sAb, long long sBb, long long sCb,
    const float* __restrict__ bias, const float* __restrict__ resid,
    u16* __restrict__ qb, u16* __restrict__ kb, u16* __restrict__ vt,
    u16* __restrict__ outb, float* __restrict__ outf) {
  const int orig = blockIdx.x;
  const int xcd = orig & 7, jj = orig >> 3;
  int id;
  if (sched == 0) {
    int pan = jj % gx, loc = jj / gx;
    id = (xcd * sp1 + loc) * gx + pan;
  } else {
    int tile = jj % gxy, bl = jj / gxy;
    id = (xcd * sp2 + bl) * gxy + tile;
  }
  const int z = id / gxy;
  const int r2 = id - z * gxy;
  const int by = r2 / gx, bx = r2 - by * gx;

  const u16* Ab = A + (size_t)z * sAb;
  const u16* Bb = Bt + (size_t)z * sBb;

  __shared__ u16 As[4][8192];
  __shared__ u16 Bs[4][8192];

  const int tid = threadIdx.x;
  const int lane = tid & 63, wid = tid >> 6;
  const int wm = wid & 1, wn = wid >> 1;
  const int l15 = lane & 15, l4 = lane >> 4;
  const int m0 = by * 256, n0 = bx * 256;

  const int lrs = tid >> 3;
  const int g0 = (tid & 7) ^ (lrs & 7);
  const int ra = (lrs << 1) | (g0 >> 2);
  const int ko = (g0 & 3) << 3;

  const int lrb = l15 >> 1;
  const int gg = ((l15 & 1) << 2) | l4;
  const int gsw = gg ^ lrb;
  const int aoff = wm * 4096 + lrb * 64 + gsw * 8;
  const int boff = (wn >> 1) * 4096 + (wn & 1) * 2048 + lrb * 64 + gsw * 8;

  f32x4 acc[8][4];
#pragma unroll
  for (int i = 0; i < 8; ++i)
#pragma unroll
    for (int j = 0; j < 4; ++j)
#pragma unroll
      for (int r = 0; r < 4; ++r) acc[i][j][r] = 0.f;

  const int NT = K >> 5;

  auto stA = [&](int sb, int t2) {
    const u16* s0 = Ab + (size_t)(m0 + ra) * K + t2 * 32 + ko;
    const u16* s1 = Ab + (size_t)(m0 + 128 + ra) * K + t2 * 32 + ko;
    gload16(s0, &As[sb][tid * 8]);
    gload16(s1, &As[sb][4096 + tid * 8]);
  };
  auto stB = [&](int sb, int t2) {
    const u16* s0 = Bb + (size_t)(n0 + ra) * K + t2 * 32 + ko;
    const u16* s1 = Bb + (size_t)(n0 + 128 + ra) * K + t2 * 32 + ko;
    gload16(s0, &Bs[sb][tid * 8]);
    gload16(s1, &Bs[sb][4096 + tid * 8]);
  };

#define TILE_BODY(P, TT, DOSTG, WN)                                            \
  do {                                                                         \
    if (DOSTG) { stA(((P) + 3) & 3, (TT) + 3); stB(((P) + 3) & 3, (TT) + 3); } \
    bf16x8 bq[4], af0[4], af1[4];                                              \
    _Pragma("unroll") for (int ni = 0; ni < 4; ++ni)                           \
        bq[ni] = *(const bf16x8*)&Bs[P][boff + ni * 512];                      \
    _Pragma("unroll") for (int i = 0; i < 4; ++i)                              \
        af0[i] = *(const bf16x8*)&As[P][aoff + i * 512];                       \
    _Pragma("unroll") for (int i = 0; i < 4; ++i)                              \
        af1[i] = *(const bf16x8*)&As[P][aoff + 2048 + i * 512];                \
    __builtin_amdgcn_s_setprio(1);                                             \
    _Pragma("unroll") for (int i = 0; i < 4; ++i)                              \
        _Pragma("unroll") for (int ni = 0; ni < 4; ++ni)                       \
            acc[i][ni] = __builtin_amdgcn_mfma_f32_16x16x32_bf16(              \
                af0[i], bq[ni], acc[i][ni], 0, 0, 0);                          \
    _Pragma("unroll") for (int i = 0; i < 4; ++i)                              \
        _Pragma("unroll") for (int ni = 0; ni < 4; ++ni)                       \
            acc[4 + i][ni] = __builtin_amdgcn_mfma_f32_16x16x32_bf16(          \
                af1[i], bq[ni], acc[4 + i][ni], 0, 0, 0);                      \
    __builtin_amdgcn_s_setprio(0);                                             \
    if ((WN) == 8) asm volatile("s_waitcnt vmcnt(8)" ::: "memory");            \
    else if ((WN) == 4) asm volatile("s_waitcnt vmcnt(4)" ::: "memory");       \
    else if ((WN) == 0) asm volatile("s_waitcnt vmcnt(0)" ::: "memory");       \
    if ((WN) >= -1) __builtin_amdgcn_s_barrier();                              \
  } while (0)

  stA(0, 0); stB(0, 0);
  stA(1, 1); stB(1, 1);
  stA(2, 2); stB(2, 2);
  asm volatile("s_waitcnt vmcnt(8)" ::: "memory");
  __builtin_amdgcn_s_barrier();

  int t = 0;
  for (; t + 7 < NT; t += 4) {
    TILE_BODY(0, t, 1, 8);
    TILE_BODY(1, t + 1, 1, 8);
    TILE_BODY(2, t + 2, 1, 8);
    TILE_BODY(3, t + 3, 1, 8);
  }
  TILE_BODY(0, t, 1, 8);
  TILE_BODY(1, t + 1, 0, 4);
  TILE_BODY(2, t + 2, 0, 0);
  TILE_BODY(3, t + 3, 0, -2);

#undef TILE_BODY

  if (EPI == 0) {
#pragma unroll
    for (int mi = 0; mi < 8; ++mi) {
#pragma unroll
      for (int ni = 0; ni < 4; ++ni) {
        const int gr0 = m0 + wm * 128 + mi * 16 + l4 * 4;
        const int gc = n0 + wn * 64 + ni * 16 + l15;
        const int bsel = gc >> 9, cin = gc & 511;
        const float bs = bias[gc];
        if (bsel < 2) {
          u16* dst = bsel ? kb : qb;
#pragma unroll
          for (int r = 0; r < 4; ++r) {
            float vvv = acc[mi][ni][r] + bs;
            if (bsel == 0) vvv *= QSCALE;
            dst[(size_t)(gr0 + r) * 512 + cin] = f2bf(vvv);
          }
        } else {
          ushort4 o;
          o.x = f2bf(acc[mi][ni][0] + bs);
          o.y = f2bf(acc[mi][ni][1] + bs);
          o.z = f2bf(acc[mi][ni][2] + bs);
          o.w = f2bf(acc[mi][ni][3] + bs);
          const int bb = gr0 >> 10, p = gr0 & 1023;
          *(ushort4*)&vt[(size_t)bb * 524288 + (size_t)cin * 1024 + p] = o;
        }
      }
    }
  } else {  // EPI == 2
#pragma unroll
    for (int mi = 0; mi < 8; ++mi) {
#pragma unroll
      for (int ni = 0; ni < 4; ++ni) {
        const int gr0 = m0 + wm * 128 + mi * 16 + l4 * 4;
        const int gc = n0 + wn * 64 + ni * 16 + l15;
#pragma unroll
        for (int r = 0; r < 4; ++r)
          outf[(size_t)(gr0 + r) * N + gc] =
              acc[mi][ni][r] + bias[gc] + resid[(size_t)(gr0 + r) * N + gc];
      }
    }
  }
}

// ---------------------------------------------------------------------------
// Fused flash attention v4: v2 structure + PV-lag-1 software pipeline.
// Per iteration i: stageK(i+1) | QK(i) MFMA | PV(i-1) MFMA (Ps dbuf makes
// this barrier-free) | loadV(i+1) into the just-consumed V reg set | exp(i)
// on VALU overlapping PV | counted vmcnt(4) | ONE barrier.
// exp + P-write leave the critical path (hidden under PV's matrix work).
// V sets va/vb alternate by 2x unroll (static reg indices). Final PV(31)
// in the epilogue. Numerics identical to v2 (__expf, QSCALE'd q).
// ---------------------------------------------------------------------------
__global__ __launch_bounds__(512, 2) void flash_k(
    const u16* __restrict__ qg, const u16* __restrict__ kg,
    const u16* __restrict__ vtg, u16* __restrict__ Og) {
  __shared__ u16 Ks[2][32 * 512];   // 64 KB
  __shared__ u16 Ps[2][128 * 40];   // 20 KB
  __shared__ float rsumS[128];

  const int tid = threadIdx.x, lane = tid & 63, wid = tid >> 6;
  const int l15 = lane & 15, l4 = lane >> 4;
  const int orig = blockIdx.x;
  const int xcd = orig & 7, jj = orig >> 3;
  const int z = xcd * 4 + (jj & 3);   // batch pinned to XCD
  const int qb0 = jj >> 2;            // q-block 0..7

  const u16* qz = qg + (size_t)(z * 1024 + qb0 * 128) * 512;
  const u16* kz = kg + (size_t)z * 1024 * 512;
  const u16* vz = vtg + (size_t)z * 512 * 1024;

  const int krow_ = tid >> 6;
  const int kgr = tid & 63;
  const int kgs = (kgr & 56) | ((kgr & 7) ^ (krow_ & 7));

  auto stageK = [&](int t, int buf) {
    const u16* src = kz + ((size_t)t * 32 + krow_) * 512 + kgs * 8;
#pragma unroll
    for (int s = 0; s < 4; ++s)
      gload16(src + (size_t)s * 8 * 512, &Ks[buf][s * 4096 + tid * 8]);
  };

  const int dbase = wid * 64;
  bf16x8 va[4], vb[4];
  auto loadV = [&](int t, bf16x8 (&dst)[4]) {
#pragma unroll
    for (int nf = 0; nf < 4; ++nf)
      dst[nf] = *(const bf16x8*)&vz[(size_t)(dbase + nf * 16 + l15) * 1024 + t * 32 + l4 * 8];
  };

  bf16x8 qf[16];
#pragma unroll
  for (int kf = 0; kf < 16; ++kf)
    qf[kf] = *(const bf16x8*)&qz[(size_t)(wid * 16 + l15) * 512 + kf * 32 + l4 * 8];

  f32x4 oacc[8][4];
#pragma unroll
  for (int i = 0; i < 8; ++i)
#pragma unroll
    for (int j = 0; j < 4; ++j)
#pragma unroll
      for (int r = 0; r < 4; ++r) oacc[i][j][r] = 0.f;
  float rsum[4] = {0.f, 0.f, 0.f, 0.f};

  // prologue: K(0) -> Ks[0], V(0) -> vb
  stageK(0, 0);
  loadV(0, vb);
  asm volatile("s_waitcnt vmcnt(4)" ::: "memory");
  __builtin_amdgcn_s_barrier();

#define FBODY(I, VPV, DOPV, PRE)                                               \
  do {                                                                         \
    const int cur = (I) & 1;                                                   \
    if (PRE) stageK((I) + 1, cur ^ 1);                                         \
    f32x4 sacc[2];                                                             \
    _Pragma("unroll") for (int nf = 0; nf < 2; ++nf)                           \
      _Pragma("unroll") for (int r = 0; r < 4; ++r) sacc[nf][r] = 0.f;         \
    __builtin_amdgcn_s_setprio(1);                                             \
    _Pragma("unroll") for (int kf = 0; kf < 16; ++kf)                          \
      _Pragma("unroll") for (int nf = 0; nf < 2; ++nf) {                       \
        const int kvr = nf * 16 + l15;                                         \
        const int g = kf * 4 + l4;                                             \
        const int gs = (g & 56) | ((g & 7) ^ (kvr & 7));                       \
        const bf16x8 bfr = *(const bf16x8*)&Ks[cur][kvr * 512 + gs * 8];       \
        sacc[nf] = __builtin_amdgcn_mfma_f32_16x16x32_bf16(qf[kf], bfr,        \
                                                           sacc[nf], 0, 0, 0);\
      }                                                                        \
    if (DOPV) {                                                                \
      _Pragma("unroll") for (int mi = 0; mi < 8; ++mi) {                       \
        const bf16x8 pa =                                                      \
            *(const bf16x8*)&Ps[cur ^ 1][(mi * 16 + l15) * 40 + l4 * 8];       \
        _Pragma("unroll") for (int nf = 0; nf < 4; ++nf)                       \
          oacc[mi][nf] = __builtin_amdgcn_mfma_f32_16x16x32_bf16(              \
              pa, VPV[nf], oacc[mi][nf], 0, 0, 0);                             \
      }                                                                        \
    }                                                                          \
    __builtin_amdgcn_s_setprio(0);                                             \
    if (PRE) loadV((I) + 1, VPV);                                              \
    _Pragma("unroll") for (int nf = 0; nf < 2; ++nf)                           \
      _Pragma("unroll") for (int r = 0; r < 4; ++r) {                          \
        const float e = __expf(sacc[nf][r]);                                   \
        rsum[r] += e;                                                          \
        Ps[cur][(wid * 16 + l4 * 4 + r) * 40 + nf * 16 + l15] = f2bf(e);       \
      }                                                                        \
    if (PRE) asm volatile("s_waitcnt vmcnt(4)" ::: "memory");                  \
    __builtin_amdgcn_s_barrier();                                              \
  } while (0)

  FBODY(0, va, 0, 1);              // QK(0); loadV(1)->va
  for (int t = 1; t < 31; t += 2) {
    FBODY(t, vb, 1, 1);            // QK(t), PV(t-1) from vb, loadV(t+1)->vb
    FBODY(t + 1, va, 1, 1);        // QK(t+1), PV(t) from va, loadV(t+2)->va
  }
  FBODY(31, vb, 1, 0);             // QK(31), PV(30) from vb
#undef FBODY

  // final PV(31): Ps[1], V(31) in va
  __builtin_amdgcn_s_setprio(1);
#pragma unroll
  for (int mi = 0; mi < 8; ++mi) {
    const bf16x8 pa = *(const bf16x8*)&Ps[1][(mi * 16 + l15) * 40 + l4 * 8];
#pragma unroll
    for (int nf = 0; nf < 4; ++nf)
      oacc[mi][nf] = __builtin_amdgcn_mfma_f32_16x16x32_bf16(pa, va[nf], oacc[mi][nf], 0, 0, 0);
  }
  __builtin_amdgcn_s_setprio(0);

  // publish per-row inverse sums
#pragma unroll
  for (int r = 0; r < 4; ++r) {
    float v = rsum[r];
    v += __shfl_xor(v, 1);
    v += __shfl_xor(v, 2);
    v += __shfl_xor(v, 4);
    v += __shfl_xor(v, 8);
    if (l15 == 0) rsumS[wid * 16 + l4 * 4 + r] = 1.0f / v;
  }
  __syncthreads();

  // store O slice scaled by 1/rowsum
  u16* ob = Og + (size_t)(z * 1024 + qb0 * 128) * 512;
#pragma unroll
  for (int mi = 0; mi < 8; ++mi) {
#pragma unroll
    for (int r = 0; r < 4; ++r) {
      const int q = mi * 16 + l4 * 4 + r;
      const float inv = rsumS[q];
#pragma unroll
      for (int nf = 0; nf < 4; ++nf)
        ob[(size_t)q * 512 + dbase + nf * 16 + l15] = f2bf(oacc[mi][nf][r] * inv);
    }
  }
}

// ---------------------------------------------------------------------------
extern "C" void kernel_launch(void* const* d_in, const int* in_sizes, int n_in,
                              void* d_out, int out_size, void* d_ws, size_t ws_size,
                              hipStream_t stream) {
  const float* x = (const float*)d_in[0];
  const float* gn_scale = (const float*)d_in[2];
  const float* gn_bias = (const float*)d_in[3];
  const float* w_qkv = (const float*)d_in[4];
  const float* b_qkv = (const float*)d_in[5];
  const float* w_out = (const float*)d_in[6];
  const float* b_out = (const float*)d_in[7];
  float* out = (float*)d_out;

  char* ws = (char*)d_ws;
  const size_t MB = 1024ull * 1024ull;
  u16* qb = (u16*)(ws + 0 * MB);      // 32 MB  [32768][512]
  u16* kb = (u16*)(ws + 32 * MB);     // 32 MB  [32768][512]
  u16* vt = (u16*)(ws + 64 * MB);     // 32 MB  [32][512][1024]  (V transposed)
  u16* zO = (u16*)(ws + 128 * MB);    // 32 MB  z, later reused as O
  u16* wqkvT = (u16*)(ws + 224 * MB); // 1.5 MB [1536][512]
  u16* woutT = (u16*)(ws + 226 * MB); // 0.5 MB [512][512]

  prep_weights<<<4096, 256, 0, stream>>>(w_qkv, w_out, wqkvT, woutT);
  groupnorm_k<<<1024, 256, 0, stream>>>(x, gn_scale, gn_bias, zO);

  // QKV: z @ wqkvT^T -> q,k (rowmajor, q scaled), v (transposed)
  gemm_ring<0><<<768, 512, 0, stream>>>(
      zO, wqkvT, 6, 768, 1536, 512, 0, 16, 0, 0, 0, 0, b_qkv, nullptr,
      qb, kb, vt, nullptr, nullptr);

  // Fused attention: O = (exp(q k^T) V) / rowsum   (writes zO)
  flash_k<<<256, 512, 0, stream>>>(qb, kb, vt, zO);

  // out = O @ w_out^T + b_out + x
  gemm_ring<2><<<256, 512, 0, stream>>>(
      zO, woutT, 2, 256, 512, 512, 0, 16, 0, 0, 0, 0, b_out, x,
      nullptr, nullptr, nullptr, nullptr, out);
}

// Round 14
// 233.920 us; speedup vs baseline: 1.3515x; 1.3515x over previous
//
#include <hip/hip_runtime.h>

typedef unsigned short u16;
typedef short bf16x8 __attribute__((ext_vector_type(8)));
typedef float f32x4 __attribute__((ext_vector_type(4)));

__device__ __forceinline__ u16 f2bf(float f) {
  union { float f; unsigned u; } c; c.f = f;
  unsigned r = (c.u + 0x7FFFu + ((c.u >> 16) & 1u)) >> 16;
  return (u16)r;
}
__device__ __forceinline__ float bf2f(u16 h) {
  union { unsigned u; float f; } c; c.u = ((unsigned)h) << 16;
  return c.f;
}
__device__ __forceinline__ void gload16(const void* g, void* l) {
  __builtin_amdgcn_global_load_lds(
      (const __attribute__((address_space(1))) unsigned*)g,
      (__attribute__((address_space(3))) unsigned*)l, 16, 0, 0);
}

// ---------------------------------------------------------------------------
// Weight prep: w_qkv [512,1536] -> wqkvT bf16 [1536,512]; w_out -> woutT [512,512]
// ---------------------------------------------------------------------------
__global__ __launch_bounds__(256) void prep_weights(
    const float* __restrict__ w_qkv, const float* __restrict__ w_out,
    u16* __restrict__ wqkvT, u16* __restrict__ woutT) {
  int i = blockIdx.x * 256 + threadIdx.x;
  const int T1 = 1536 * 512;
  if (i < T1) {
    int n = i >> 9, c = i & 511;
    wqkvT[i] = f2bf(w_qkv[(size_t)c * 1536 + n]);
  } else {
    int j = i - T1;
    int n = j >> 9, c = j & 511;
    woutT[j] = f2bf(w_out[(size_t)c * 512 + n]);
  }
}

// ---------------------------------------------------------------------------
// GroupNorm: x fp32 [32,1024,512] -> z bf16; 32 groups of 16 ch
// ---------------------------------------------------------------------------
__global__ __launch_bounds__(256) void groupnorm_k(
    const float* __restrict__ x, const float* __restrict__ scale,
    const float* __restrict__ bias, u16* __restrict__ z) {
  const int blk = blockIdx.x, b = blk >> 5, g = blk & 31;
  const float* xb = x + (size_t)b * 524288 + g * 16;
  u16* zb = z + (size_t)b * 524288 + g * 16;
  const int tid = threadIdx.x, lane = tid & 63, wid = tid >> 6;

  float4 vv[16];
  float s = 0.f, ss = 0.f;
#pragma unroll
  for (int i = 0; i < 16; ++i) {
    int e = (i * 256 + tid) * 4;
    int hw = e >> 4, j = e & 15;
    vv[i] = *(const float4*)&xb[(size_t)hw * 512 + j];
    s += vv[i].x + vv[i].y + vv[i].z + vv[i].w;
    ss += vv[i].x * vv[i].x + vv[i].y * vv[i].y + vv[i].z * vv[i].z + vv[i].w * vv[i].w;
  }
#pragma unroll
  for (int off = 32; off; off >>= 1) {
    s += __shfl_xor(s, off);
    ss += __shfl_xor(ss, off);
  }
  __shared__ float rs[4], rq[4];
  if (!lane) { rs[wid] = s; rq[wid] = ss; }
  __syncthreads();
  float S_ = rs[0] + rs[1] + rs[2] + rs[3];
  float Q_ = rq[0] + rq[1] + rq[2] + rq[3];
  const float inv_n = 1.f / 16384.f;
  float mean = S_ * inv_n;
  float var = Q_ * inv_n - mean * mean;
  float rstd = rsqrtf(var + 1e-5f);

  int j0 = (tid * 4) & 15;
  float sc0 = scale[g * 16 + j0 + 0] * rstd, sc1 = scale[g * 16 + j0 + 1] * rstd;
  float sc2 = scale[g * 16 + j0 + 2] * rstd, sc3 = scale[g * 16 + j0 + 3] * rstd;
  float bi0 = bias[g * 16 + j0 + 0] - mean * sc0, bi1 = bias[g * 16 + j0 + 1] - mean * sc1;
  float bi2 = bias[g * 16 + j0 + 2] - mean * sc2, bi3 = bias[g * 16 + j0 + 3] - mean * sc3;
#pragma unroll
  for (int i = 0; i < 16; ++i) {
    int e = (i * 256 + tid) * 4;
    int hw = e >> 4, j = e & 15;
    ushort4 o;
    o.x = f2bf(vv[i].x * sc0 + bi0);
    o.y = f2bf(vv[i].y * sc1 + bi1);
    o.z = f2bf(vv[i].z * sc2 + bi2);
    o.w = f2bf(vv[i].w * sc3 + bi3);
    *(ushort4*)&zb[(size_t)hw * 512 + j] = o;
  }
}

// ---------------------------------------------------------------------------
// Deep-ring GEMM (round-9 structure): 256x256 tile, BK=32, 4-buffer ring,
// 1 barrier + counted vmcnt(8) per tile.
// EPI 0: q (scaled by 1/sqrt(512)), k rowmajor, v -> TRANSPOSED [b][c][p]
// EPI 2: fp32 +bias+resid
// ---------------------------------------------------------------------------
#define QSCALE 0.04419417382415922f

template <int EPI>
__global__ __launch_bounds__(512, 2) void gemm_ring(
    const u16* __restrict__ A, const u16* __restrict__ Bt,
    int gx, int gxy, int N, int K,
    int sched, int sp1, int sp2,
    long long sAb, long long sBb, long long sCb,
    const float* __restrict__ bias, const float* __restrict__ resid,
    u16* __restrict__ qb, u16* __restrict__ kb, u16* __restrict__ vt,
    u16* __restrict__ outb, float* __restrict__ outf) {
  const int orig = blockIdx.x;
  const int xcd = orig & 7, jj = orig >> 3;
  int id;
  if (sched == 0) {
    int pan = jj % gx, loc = jj / gx;
    id = (xcd * sp1 + loc) * gx + pan;
  } else {
    int tile = jj % gxy, bl = jj / gxy;
    id = (xcd * sp2 + bl) * gxy + tile;
  }
  const int z = id / gxy;
  const int r2 = id - z * gxy;
  const int by = r2 / gx, bx = r2 - by * gx;

  const u16* Ab = A + (size_t)z * sAb;
  const u16* Bb = Bt + (size_t)z * sBb;

  __shared__ u16 As[4][8192];
  __shared__ u16 Bs[4][8192];

  const int tid = threadIdx.x;
  const int lane = tid & 63, wid = tid >> 6;
  const int wm = wid & 1, wn = wid >> 1;
  const int l15 = lane & 15, l4 = lane >> 4;
  const int m0 = by * 256, n0 = bx * 256;

  const int lrs = tid >> 3;
  const int g0 = (tid & 7) ^ (lrs & 7);
  const int ra = (lrs << 1) | (g0 >> 2);
  const int ko = (g0 & 3) << 3;

  const int lrb = l15 >> 1;
  const int gg = ((l15 & 1) << 2) | l4;
  const int gsw = gg ^ lrb;
  const int aoff = wm * 4096 + lrb * 64 + gsw * 8;
  const int boff = (wn >> 1) * 4096 + (wn & 1) * 2048 + lrb * 64 + gsw * 8;

  f32x4 acc[8][4];
#pragma unroll
  for (int i = 0; i < 8; ++i)
#pragma unroll
    for (int j = 0; j < 4; ++j)
#pragma unroll
      for (int r = 0; r < 4; ++r) acc[i][j][r] = 0.f;

  const int NT = K >> 5;

  auto stA = [&](int sb, int t2) {
    const u16* s0 = Ab + (size_t)(m0 + ra) * K + t2 * 32 + ko;
    const u16* s1 = Ab + (size_t)(m0 + 128 + ra) * K + t2 * 32 + ko;
    gload16(s0, &As[sb][tid * 8]);
    gload16(s1, &As[sb][4096 + tid * 8]);
  };
  auto stB = [&](int sb, int t2) {
    const u16* s0 = Bb + (size_t)(n0 + ra) * K + t2 * 32 + ko;
    const u16* s1 = Bb + (size_t)(n0 + 128 + ra) * K + t2 * 32 + ko;
    gload16(s0, &Bs[sb][tid * 8]);
    gload16(s1, &Bs[sb][4096 + tid * 8]);
  };

#define TILE_BODY(P, TT, DOSTG, WN)                                            \
  do {                                                                         \
    if (DOSTG) { stA(((P) + 3) & 3, (TT) + 3); stB(((P) + 3) & 3, (TT) + 3); } \
    bf16x8 bq[4], af0[4], af1[4];                                              \
    _Pragma("unroll") for (int ni = 0; ni < 4; ++ni)                           \
        bq[ni] = *(const bf16x8*)&Bs[P][boff + ni * 512];                      \
    _Pragma("unroll") for (int i = 0; i < 4; ++i)                              \
        af0[i] = *(const bf16x8*)&As[P][aoff + i * 512];                       \
    _Pragma("unroll") for (int i = 0; i < 4; ++i)                              \
        af1[i] = *(const bf16x8*)&As[P][aoff + 2048 + i * 512];                \
    __builtin_amdgcn_s_setprio(1);                                             \
    _Pragma("unroll") for (int i = 0; i < 4; ++i)                              \
        _Pragma("unroll") for (int ni = 0; ni < 4; ++ni)                       \
            acc[i][ni] = __builtin_amdgcn_mfma_f32_16x16x32_bf16(              \
                af0[i], bq[ni], acc[i][ni], 0, 0, 0);                          \
    _Pragma("unroll") for (int i = 0; i < 4; ++i)                              \
        _Pragma("unroll") for (int ni = 0; ni < 4; ++ni)                       \
            acc[4 + i][ni] = __builtin_amdgcn_mfma_f32_16x16x32_bf16(          \
                af1[i], bq[ni], acc[4 + i][ni], 0, 0, 0);                      \
    __builtin_amdgcn_s_setprio(0);                                             \
    if ((WN) == 8) asm volatile("s_waitcnt vmcnt(8)" ::: "memory");            \
    else if ((WN) == 4) asm volatile("s_waitcnt vmcnt(4)" ::: "memory");       \
    else if ((WN) == 0) asm volatile("s_waitcnt vmcnt(0)" ::: "memory");       \
    if ((WN) >= -1) __builtin_amdgcn_s_barrier();                              \
  } while (0)

  stA(0, 0); stB(0, 0);
  stA(1, 1); stB(1, 1);
  stA(2, 2); stB(2, 2);
  asm volatile("s_waitcnt vmcnt(8)" ::: "memory");
  __builtin_amdgcn_s_barrier();

  int t = 0;
  for (; t + 7 < NT; t += 4) {
    TILE_BODY(0, t, 1, 8);
    TILE_BODY(1, t + 1, 1, 8);
    TILE_BODY(2, t + 2, 1, 8);
    TILE_BODY(3, t + 3, 1, 8);
  }
  TILE_BODY(0, t, 1, 8);
  TILE_BODY(1, t + 1, 0, 4);
  TILE_BODY(2, t + 2, 0, 0);
  TILE_BODY(3, t + 3, 0, -2);

#undef TILE_BODY

  if (EPI == 0) {
#pragma unroll
    for (int mi = 0; mi < 8; ++mi) {
#pragma unroll
      for (int ni = 0; ni < 4; ++ni) {
        const int gr0 = m0 + wm * 128 + mi * 16 + l4 * 4;
        const int gc = n0 + wn * 64 + ni * 16 + l15;
        const int bsel = gc >> 9, cin = gc & 511;
        const float bs = bias[gc];
        if (bsel < 2) {
          u16* dst = bsel ? kb : qb;
#pragma unroll
          for (int r = 0; r < 4; ++r) {
            float vvv = acc[mi][ni][r] + bs;
            if (bsel == 0) vvv *= QSCALE;
            dst[(size_t)(gr0 + r) * 512 + cin] = f2bf(vvv);
          }
        } else {
          ushort4 o;
          o.x = f2bf(acc[mi][ni][0] + bs);
          o.y = f2bf(acc[mi][ni][1] + bs);
          o.z = f2bf(acc[mi][ni][2] + bs);
          o.w = f2bf(acc[mi][ni][3] + bs);
          const int bb = gr0 >> 10, p = gr0 & 1023;
          *(ushort4*)&vt[(size_t)bb * 524288 + (size_t)cin * 1024 + p] = o;
        }
      }
    }
  } else {  // EPI == 2
#pragma unroll
    for (int mi = 0; mi < 8; ++mi) {
#pragma unroll
      for (int ni = 0; ni < 4; ++ni) {
        const int gr0 = m0 + wm * 128 + mi * 16 + l4 * 4;
        const int gc = n0 + wn * 64 + ni * 16 + l15;
#pragma unroll
        for (int r = 0; r < 4; ++r)
          outf[(size_t)(gr0 + r) * N + gc] =
              acc[mi][ni][r] + bias[gc] + resid[(size_t)(gr0 + r) * N + gc];
      }
    }
  }
}

// ---------------------------------------------------------------------------
// Fused flash attention v2 (round-11, proven 94 us): no-max softmax,
// O = (exp(q@k^T) @ V) / rowsum.  Grid 256 = 32 batches x 8 q-blocks(128);
// 512 thr = 8 waves.
// QK: wave owns 16 q-rows (Q in regs): S[16q x 32kv], 32 MFMA, swizzled Ks.
// exp -> SHARED P dbuf [2][128][40] + lane-local rsum.
// PV (d-split): wave owns d-slice [wid*64,+64) over ALL 128 q: 8 P-frag
// reads + V in REGISTERS (prefetched 1 tile ahead from vt[z][d][p]).
// One barrier/tile (publishes P[cur] + K DMA for t+1, vmcnt(4) counted).
// ---------------------------------------------------------------------------
__global__ __launch_bounds__(512, 2) void flash_k(
    const u16* __restrict__ qg, const u16* __restrict__ kg,
    const u16* __restrict__ vtg, u16* __restrict__ Og) {
  __shared__ u16 Ks[2][32 * 512];   // 64 KB
  __shared__ u16 Ps[2][128 * 40];   // 20 KB (stride 40 u16 = 80B)
  __shared__ float rsumS[128];

  const int tid = threadIdx.x, lane = tid & 63, wid = tid >> 6;
  const int l15 = lane & 15, l4 = lane >> 4;
  const int orig = blockIdx.x;
  const int xcd = orig & 7, jj = orig >> 3;
  const int z = xcd * 4 + (jj & 3);   // batch pinned to XCD
  const int qb0 = jj >> 2;            // q-block 0..7

  const u16* qz = qg + (size_t)(z * 1024 + qb0 * 128) * 512;
  const u16* kz = kg + (size_t)z * 1024 * 512;
  const u16* vz = vtg + (size_t)z * 512 * 1024;

  // K staging: granule-XOR pre-swizzled source (read swizzle matches)
  const int krow_ = tid >> 6;
  const int kgr = tid & 63;
  const int kgs = (kgr & 56) | ((kgr & 7) ^ (krow_ & 7));

  auto stageK = [&](int t, int buf) {
    const u16* src = kz + ((size_t)t * 32 + krow_) * 512 + kgs * 8;
#pragma unroll
    for (int s = 0; s < 4; ++s)
      gload16(src + (size_t)s * 8 * 512, &Ks[buf][s * 4096 + tid * 8]);
  };

  // V d-slice direct-to-register (wave owns d in [wid*64, wid*64+64))
  const int dbase = wid * 64;
  bf16x8 vcur[4], vnxt[4];
  auto loadV = [&](int t, bf16x8* dst) {
#pragma unroll
    for (int nf = 0; nf < 4; ++nf)
      dst[nf] = *(const bf16x8*)&vz[(size_t)(dbase + nf * 16 + l15) * 1024 + t * 32 + l4 * 8];
  };

  // Q fragments: wave's 16 q-rows x 512 k (64 VGPR)
  bf16x8 qf[16];
#pragma unroll
  for (int kf = 0; kf < 16; ++kf)
    qf[kf] = *(const bf16x8*)&qz[(size_t)(wid * 16 + l15) * 512 + kf * 32 + l4 * 8];

  f32x4 oacc[8][4];   // O slice [128 q][64 d]: [mi][nf]
#pragma unroll
  for (int i = 0; i < 8; ++i)
#pragma unroll
    for (int j = 0; j < 4; ++j)
#pragma unroll
      for (int r = 0; r < 4; ++r) oacc[i][j][r] = 0.f;
  float rsum[4] = {0.f, 0.f, 0.f, 0.f};

  // prologue
  stageK(0, 0);
  loadV(0, vcur);
  asm volatile("s_waitcnt vmcnt(4)" ::: "memory");  // K(0) done; V(0) by dep
  __builtin_amdgcn_s_barrier();

  for (int t = 0; t < 32; ++t) {
    const int cur = t & 1;
    const bool pre = (t + 1 < 32);
    if (pre) { stageK(t + 1, cur ^ 1); loadV(t + 1, vnxt); }

    // QK: S[16q x 32kv] for this wave's q-rows
    f32x4 sacc[2];
#pragma unroll
    for (int nf = 0; nf < 2; ++nf)
#pragma unroll
      for (int r = 0; r < 4; ++r) sacc[nf][r] = 0.f;
#pragma unroll
    for (int kf = 0; kf < 16; ++kf) {
#pragma unroll
      for (int nf = 0; nf < 2; ++nf) {
        const int kvr = nf * 16 + l15;
        const int g = kf * 4 + l4;
        const int gs = (g & 56) | ((g & 7) ^ (kvr & 7));
        const bf16x8 bfr = *(const bf16x8*)&Ks[cur][kvr * 512 + gs * 8];
        sacc[nf] = __builtin_amdgcn_mfma_f32_16x16x32_bf16(qf[kf], bfr, sacc[nf], 0, 0, 0);
      }
    }

    // exp -> shared P[cur] + lane-local row-sum partials
#pragma unroll
    for (int nf = 0; nf < 2; ++nf)
#pragma unroll
      for (int r = 0; r < 4; ++r) {
        const float e = __expf(sacc[nf][r]);
        rsum[r] += e;
        Ps[cur][(wid * 16 + l4 * 4 + r) * 40 + nf * 16 + l15] = f2bf(e);
      }

    if (pre) asm volatile("s_waitcnt vmcnt(4)" ::: "memory");  // K(t+1) landed
    __builtin_amdgcn_s_barrier();   // publish P[cur] + Ks[cur^1]

    // PV: O[128q x 64d-slice] += P[cur] @ V(regs)
    __builtin_amdgcn_s_setprio(1);
#pragma unroll
    for (int mi = 0; mi < 8; ++mi) {
      const bf16x8 pa = *(const bf16x8*)&Ps[cur][(mi * 16 + l15) * 40 + l4 * 8];
#pragma unroll
      for (int nf = 0; nf < 4; ++nf)
        oacc[mi][nf] = __builtin_amdgcn_mfma_f32_16x16x32_bf16(pa, vcur[nf], oacc[mi][nf], 0, 0, 0);
    }
    __builtin_amdgcn_s_setprio(0);

    if (pre) {
#pragma unroll
      for (int nf = 0; nf < 4; ++nf) vcur[nf] = vnxt[nf];
    }
  }

  // publish per-row inverse sums
#pragma unroll
  for (int r = 0; r < 4; ++r) {
    float v = rsum[r];
    v += __shfl_xor(v, 1);
    v += __shfl_xor(v, 2);
    v += __shfl_xor(v, 4);
    v += __shfl_xor(v, 8);
    if (l15 == 0) rsumS[wid * 16 + l4 * 4 + r] = 1.0f / v;
  }
  __syncthreads();

  // store O slice scaled by 1/rowsum
  u16* ob = Og + (size_t)(z * 1024 + qb0 * 128) * 512;
#pragma unroll
  for (int mi = 0; mi < 8; ++mi) {
#pragma unroll
    for (int r = 0; r < 4; ++r) {
      const int q = mi * 16 + l4 * 4 + r;
      const float inv = rsumS[q];
#pragma unroll
      for (int nf = 0; nf < 4; ++nf)
        ob[(size_t)q * 512 + dbase + nf * 16 + l15] = f2bf(oacc[mi][nf][r] * inv);
    }
  }
}

// ---------------------------------------------------------------------------
extern "C" void kernel_launch(void* const* d_in, const int* in_sizes, int n_in,
                              void* d_out, int out_size, void* d_ws, size_t ws_size,
                              hipStream_t stream) {
  const float* x = (const float*)d_in[0];
  const float* gn_scale = (const float*)d_in[2];
  const float* gn_bias = (const float*)d_in[3];
  const float* w_qkv = (const float*)d_in[4];
  const float* b_qkv = (const float*)d_in[5];
  const float* w_out = (const float*)d_in[6];
  const float* b_out = (const float*)d_in[7];
  float* out = (float*)d_out;

  char* ws = (char*)d_ws;
  const size_t MB = 1024ull * 1024ull;
  u16* qb = (u16*)(ws + 0 * MB);      // 32 MB  [32768][512]
  u16* kb = (u16*)(ws + 32 * MB);     // 32 MB  [32768][512]
  u16* vt = (u16*)(ws + 64 * MB);     // 32 MB  [32][512][1024]  (V transposed)
  u16* zO = (u16*)(ws + 128 * MB);    // 32 MB  z, later reused as O
  u16* wqkvT = (u16*)(ws + 224 * MB); // 1.5 MB [1536][512]
  u16* woutT = (u16*)(ws + 226 * MB); // 0.5 MB [512][512]

  prep_weights<<<4096, 256, 0, stream>>>(w_qkv, w_out, wqkvT, woutT);
  groupnorm_k<<<1024, 256, 0, stream>>>(x, gn_scale, gn_bias, zO);

  // QKV: z @ wqkvT^T -> q,k (rowmajor, q scaled), v (transposed)
  gemm_ring<0><<<768, 512, 0, stream>>>(
      zO, wqkvT, 6, 768, 1536, 512, 0, 16, 0, 0, 0, 0, b_qkv, nullptr,
      qb, kb, vt, nullptr, nullptr);

  // Fused attention: O = (exp(q k^T) V) / rowsum   (writes zO)
  flash_k<<<256, 512, 0, stream>>>(qb, kb, vt, zO);

  // out = O @ w_out^T + b_out + x
  gemm_ring<2><<<256, 512, 0, stream>>>(
      zO, woutT, 2, 256, 512, 512, 0, 16, 0, 0, 0, 0, b_out, x,
      nullptr, nullptr, nullptr, nullptr, out);
}